// Round 4
// baseline (286.320 us; speedup 1.0000x reference)
//
#include <hip/hip_runtime.h>

#define IMG_H 256
#define IMG_W 256
#define ROWS 8
#define STRIPS (IMG_H / ROWS)      // 32 strips per image
#define NIMG 128
#define NWAVES (NIMG * STRIPS)     // 4096 waves, one per 8-row strip

__device__ __forceinline__ float pullf(int addr, float v) {
    return __int_as_float(__builtin_amdgcn_ds_bpermute(addr, __float_as_int(v)));
}

__device__ __forceinline__ float4 f4fma(float w, float4 a, float4 b) {
    return make_float4(fmaf(w, a.x, b.x), fmaf(w, a.y, b.y),
                       fmaf(w, a.z, b.z), fmaf(w, a.w, b.w));
}

__device__ __forceinline__ float4 f4mul(float4 a, float4 b) {
    return make_float4(a.x * b.x, a.y * b.y, a.z * b.z, a.w * b.w);
}

__device__ __forceinline__ float4 f4scale(float w, float4 a) {
    return make_float4(w * a.x, w * a.y, w * a.z, w * a.w);
}

__device__ __forceinline__ float ssim1(float mu1, float mu2, float spp, float stt, float spt) {
    const float C1 = 1e-4f, C2 = 9e-4f;
    float mu1s = mu1 * mu1, mu2s = mu2 * mu2, mu12 = mu1 * mu2;
    float s1 = spp - mu1s, s2 = stt - mu2s, s12 = spt - mu12;
    float num = (2.f * mu12 + C1) * (2.f * s12 + C2);
    float den = (mu1s + mu2s + C1) * (s1 + s2 + C2);
    return num * __builtin_amdgcn_rcpf(den);   // rel err ~1e-6 << 2e-2 threshold
}

// V-first separable SSIM. One wave = one 8-row strip, float4/lane = 256 cols.
// Window stores RAW rows only (2 arrays x 8 slots = 64 VGPR), mod-8 slots.
// Per output row: 5 vertical 7-tap convs (products recomputed per tap),
// then horizontal 7-tap via 6 ds_bpermute per quantity. No LDS, no syncs.
// __launch_bounds__(256,4): force <=128 VGPR => 4 waves/SIMD.
template<int ATOMIC>
__global__ __launch_bounds__(256, 4) void ssim_main(
    const float* __restrict__ pred,
    const float* __restrict__ targ,
    const float* __restrict__ window,
    float* __restrict__ wsum)
{
    const int lane = threadIdx.x & 63;
    const int wid  = threadIdx.x >> 6;
    const int gw   = blockIdx.x * 4 + wid;   // 0..4095
    const int n    = gw >> 5;                // image
    const int s    = gw & 31;                // strip
    const int r0   = s * ROWS;
    const int c    = lane << 2;

    // exact 1D gaussian: g[j] = w2d[3][j] / sum_j w2d[3][j]
    float g[7];
    {
        float sum = 0.f;
#pragma unroll
        for (int j = 0; j < 7; ++j) { g[j] = window[21 + j]; sum += g[j]; }
        float inv = 1.f / sum;
#pragma unroll
        for (int j = 0; j < 7; ++j) g[j] *= inv;
    }

    const float* pn = pred + (size_t)n * (IMG_H * IMG_W) + c;
    const float* tn = targ + (size_t)n * (IMG_H * IMG_W) + c;

    const int a_up = ((lane - 1) & 63) << 2;
    const int a_dn = ((lane + 1) & 63) << 2;
    const bool l0  = (lane == 0);
    const bool l63 = (lane == 63);

    float4 WP[8], WT[8];        // raw row window, slot = (j - (r0-3)) & 7
    float acc = 0.f;

#define LOADROW(SLOT, J) { \
    const int j_ = (J); \
    if ((unsigned)j_ < (unsigned)IMG_H) { \
        WP[SLOT] = *(const float4*)(pn + j_ * IMG_W); \
        WT[SLOT] = *(const float4*)(tn + j_ * IMG_W); \
    } else { \
        WP[SLOT] = make_float4(0.f, 0.f, 0.f, 0.f); \
        WT[SLOT] = make_float4(0.f, 0.f, 0.f, 0.f); \
    } }

// vertical 7-tap of one raw array
#define VPASS1(D, OUTV, ARR) { \
    OUTV = f4scale(g[0], ARR[(D) & 7]); \
    OUTV = f4fma(g[1], ARR[((D) + 1) & 7], OUTV); \
    OUTV = f4fma(g[2], ARR[((D) + 2) & 7], OUTV); \
    OUTV = f4fma(g[3], ARR[((D) + 3) & 7], OUTV); \
    OUTV = f4fma(g[4], ARR[((D) + 4) & 7], OUTV); \
    OUTV = f4fma(g[5], ARR[((D) + 5) & 7], OUTV); \
    OUTV = f4fma(g[6], ARR[((D) + 6) & 7], OUTV); }

// vertical 7-tap of elementwise product A*B (recomputed per tap)
#define VPASS2(D, OUTV, A, B) { \
    OUTV = f4scale(g[0], f4mul(A[(D) & 7], B[(D) & 7])); \
    OUTV = f4fma(g[1], f4mul(A[((D) + 1) & 7], B[((D) + 1) & 7]), OUTV); \
    OUTV = f4fma(g[2], f4mul(A[((D) + 2) & 7], B[((D) + 2) & 7]), OUTV); \
    OUTV = f4fma(g[3], f4mul(A[((D) + 3) & 7], B[((D) + 3) & 7]), OUTV); \
    OUTV = f4fma(g[4], f4mul(A[((D) + 4) & 7], B[((D) + 4) & 7]), OUTV); \
    OUTV = f4fma(g[5], f4mul(A[((D) + 5) & 7], B[((D) + 5) & 7]), OUTV); \
    OUTV = f4fma(g[6], f4mul(A[((D) + 6) & 7], B[((D) + 6) & 7]), OUTV); }

// horizontal 7-tap: gather 3+3 halo cols via bpermute, 4 fma chains
#define HCONV(V, OUT) { \
    float m3 = l0  ? 0.f : pullf(a_up, (V).y); \
    float m2 = l0  ? 0.f : pullf(a_up, (V).z); \
    float m1 = l0  ? 0.f : pullf(a_up, (V).w); \
    float q4 = l63 ? 0.f : pullf(a_dn, (V).x); \
    float q5 = l63 ? 0.f : pullf(a_dn, (V).y); \
    float q6 = l63 ? 0.f : pullf(a_dn, (V).z); \
    (OUT).x = fmaf(g[0], m3, fmaf(g[1], m2, fmaf(g[2], m1, fmaf(g[3], (V).x, \
              fmaf(g[4], (V).y, fmaf(g[5], (V).z, g[6] * (V).w)))))); \
    (OUT).y = fmaf(g[0], m2, fmaf(g[1], m1, fmaf(g[2], (V).x, fmaf(g[3], (V).y, \
              fmaf(g[4], (V).z, fmaf(g[5], (V).w, g[6] * q4)))))); \
    (OUT).z = fmaf(g[0], m1, fmaf(g[1], (V).x, fmaf(g[2], (V).y, fmaf(g[3], (V).z, \
              fmaf(g[4], (V).w, fmaf(g[5], q4, g[6] * q5)))))); \
    (OUT).w = fmaf(g[0], (V).x, fmaf(g[1], (V).y, fmaf(g[2], (V).z, fmaf(g[3], (V).w, \
              fmaf(g[4], q4, fmaf(g[5], q5, g[6] * q6)))))); }

// one output row r0+D (D = 0..7 compile-time). Loads next row (one step of
// cover). V-passes and H-convs interleaved so bpermute latency hides under
// independent VALU work.
#define STEP(D, DOLOAD) { \
    if (DOLOAD) { LOADROW(((D) + 7) & 7, r0 + (D) + 4); } \
    float4 v0, v1, v2, v3, v4; \
    float4 h0, h1, h2, h3, h4; \
    VPASS1(D, v0, WP); \
    VPASS1(D, v1, WT); \
    HCONV(v0, h0); \
    VPASS2(D, v2, WP, WP); \
    HCONV(v1, h1); \
    VPASS2(D, v3, WT, WT); \
    HCONV(v2, h2); \
    VPASS2(D, v4, WP, WT); \
    HCONV(v3, h3); \
    HCONV(v4, h4); \
    float s0_ = ssim1(h0.x, h1.x, h2.x, h3.x, h4.x); \
    float s1_ = ssim1(h0.y, h1.y, h2.y, h3.y, h4.y); \
    float s2_ = ssim1(h0.z, h1.z, h2.z, h3.z, h4.z); \
    float s3_ = ssim1(h0.w, h1.w, h2.w, h3.w, h4.w); \
    acc += (s0_ + s1_) + (s2_ + s3_); }

    // prologue: pure loads, rows r0-3 .. r0+3 -> slots 0..6
    LOADROW(0, r0 - 3) LOADROW(1, r0 - 2) LOADROW(2, r0 - 1)
    LOADROW(3, r0)     LOADROW(4, r0 + 1) LOADROW(5, r0 + 2)
    LOADROW(6, r0 + 3)

    STEP(0, 1) STEP(1, 1) STEP(2, 1) STEP(3, 1)
    STEP(4, 1) STEP(5, 1) STEP(6, 1) STEP(7, 0)

#undef LOADROW
#undef VPASS1
#undef VPASS2
#undef HCONV
#undef STEP

    // wave-local reduce, one write (or atomic) per wave
#pragma unroll
    for (int off = 32; off > 0; off >>= 1)
        acc += __shfl_xor(acc, off, 64);
    if (lane == 0) {
        if (ATOMIC) atomicAdd(&wsum[0], acc);
        else        wsum[gw] = acc;
    }
}

// deterministic f64 tree-reduce of the 4096 per-wave partials
__global__ __launch_bounds__(256) void ssim_final_arr(
    const float* __restrict__ ws, float* __restrict__ out)
{
    __shared__ double sred[4];
    double sm = 0.0;
#pragma unroll
    for (int k = 0; k < NWAVES / 256; ++k)
        sm += (double)ws[threadIdx.x + k * 256];
#pragma unroll
    for (int off = 32; off > 0; off >>= 1)
        sm += __shfl_down(sm, off, 64);
    const int lane = threadIdx.x & 63, wid = threadIdx.x >> 6;
    if (lane == 0) sred[wid] = sm;
    __syncthreads();
    if (threadIdx.x == 0) {
        double tot = sred[0] + sred[1] + sred[2] + sred[3];
        out[0] = (float)(1.0 - tot * (1.0 / (128.0 * 256.0 * 256.0)));
    }
}

__global__ void ssim_final_sc(const float* __restrict__ ws, float* __restrict__ out)
{
    out[0] = 1.0f - ws[0] * (1.0f / (128.0f * 256.0f * 256.0f));
}

extern "C" void kernel_launch(void* const* d_in, const int* in_sizes, int n_in,
                              void* d_out, int out_size, void* d_ws, size_t ws_size,
                              hipStream_t stream)
{
    const float* pred   = (const float*)d_in[0];
    const float* targ   = (const float*)d_in[1];
    const float* window = (const float*)d_in[2];
    float* out = (float*)d_out;
    float* ws  = (float*)d_ws;

    if (ws_size >= NWAVES * sizeof(float)) {
        // every ws slot is written by the grid each call: no memset needed
        ssim_main<0><<<NWAVES / 4, 256, 0, stream>>>(pred, targ, window, ws);
        ssim_final_arr<<<1, 256, 0, stream>>>(ws, out);
    } else {
        hipMemsetAsync(ws, 0, sizeof(float), stream);
        ssim_main<1><<<NWAVES / 4, 256, 0, stream>>>(pred, targ, window, ws);
        ssim_final_sc<<<1, 1, 0, stream>>>(ws, out);
    }
    (void)in_sizes; (void)n_in; (void)out_size;
}

// Round 5
// 285.852 us; speedup vs baseline: 1.0016x; 1.0016x over previous
//
#include <hip/hip_runtime.h>

#define IMG_H 256
#define IMG_W 256
#define ROWS 8
#define STRIPS (IMG_H / ROWS)      // 32 strips per image
#define NIMG 128
#define NWAVES (NIMG * STRIPS)     // 4096 waves, one per 8-row strip

__device__ __forceinline__ float pullf(int addr, float v) {
    return __int_as_float(__builtin_amdgcn_ds_bpermute(addr, __float_as_int(v)));
}

__device__ __forceinline__ float4 f4fma(float w, float4 a, float4 b) {
    return make_float4(fmaf(w, a.x, b.x), fmaf(w, a.y, b.y),
                       fmaf(w, a.z, b.z), fmaf(w, a.w, b.w));
}

__device__ __forceinline__ float4 f4mul(float4 a, float4 b) {
    return make_float4(a.x * b.x, a.y * b.y, a.z * b.z, a.w * b.w);
}

__device__ __forceinline__ float4 f4scale(float w, float4 a) {
    return make_float4(w * a.x, w * a.y, w * a.z, w * a.w);
}

__device__ __forceinline__ float ssim1(float mu1, float mu2, float spp, float stt, float spt) {
    const float C1 = 1e-4f, C2 = 9e-4f;
    float mu1s = mu1 * mu1, mu2s = mu2 * mu2, mu12 = mu1 * mu2;
    float s1 = spp - mu1s, s2 = stt - mu2s, s12 = spt - mu12;
    float num = (2.f * mu12 + C1) * (2.f * s12 + C2);
    float den = (mu1s + mu2s + C1) * (s1 + s2 + C2);
    return num * __builtin_amdgcn_rcpf(den);   // rel err ~1e-6; absmax margin is ref-side
}

// V-first separable SSIM. One wave = one 8-row strip, float4/lane = 256 cols.
// Window: RAW rows only (2 x 8 slots x float4 = 64 VGPR), mod-8 slots, all
// static indices. Per output row the 5 quantities are computed SEQUENTIALLY
// (v reused) so peak live regs stay ~115 < 128 cap. No LDS, no syncthreads.
template<int ATOMIC>
__global__ __launch_bounds__(256, 4) void ssim_main(
    const float* __restrict__ pred,
    const float* __restrict__ targ,
    const float* __restrict__ window,
    float* __restrict__ wsum)
{
    const int lane = threadIdx.x & 63;
    const int wid  = threadIdx.x >> 6;
    const int gw   = blockIdx.x * 4 + wid;   // 0..4095
    const int n    = gw >> 5;                // image
    const int s    = gw & 31;                // strip
    const int r0   = s * ROWS;
    const int c    = lane << 2;

    // exact 1D gaussian: g[j] = w2d[3][j] / sum_j w2d[3][j]
    float g[7];
    {
        float sum = 0.f;
#pragma unroll
        for (int j = 0; j < 7; ++j) { g[j] = window[21 + j]; sum += g[j]; }
        float inv = 1.f / sum;
#pragma unroll
        for (int j = 0; j < 7; ++j) g[j] *= inv;
    }

    const float* pn = pred + (size_t)n * (IMG_H * IMG_W) + c;
    const float* tn = targ + (size_t)n * (IMG_H * IMG_W) + c;

    const int a_up = ((lane - 1) & 63) << 2;
    const int a_dn = ((lane + 1) & 63) << 2;
    const bool l0  = (lane == 0);
    const bool l63 = (lane == 63);

    float4 WP[8], WT[8];        // slot = (j - (r0-3)) & 7
    float acc = 0.f;

#define LOADROW(SLOT, J) { \
    const int j_ = (J); \
    if ((unsigned)j_ < (unsigned)IMG_H) { \
        WP[SLOT] = *(const float4*)(pn + j_ * IMG_W); \
        WT[SLOT] = *(const float4*)(tn + j_ * IMG_W); \
    } else { \
        WP[SLOT] = make_float4(0.f, 0.f, 0.f, 0.f); \
        WT[SLOT] = make_float4(0.f, 0.f, 0.f, 0.f); \
    } }

#define VPASS1(D, OUTV, ARR) { \
    OUTV = f4scale(g[0], ARR[(D) & 7]); \
    OUTV = f4fma(g[1], ARR[((D) + 1) & 7], OUTV); \
    OUTV = f4fma(g[2], ARR[((D) + 2) & 7], OUTV); \
    OUTV = f4fma(g[3], ARR[((D) + 3) & 7], OUTV); \
    OUTV = f4fma(g[4], ARR[((D) + 4) & 7], OUTV); \
    OUTV = f4fma(g[5], ARR[((D) + 5) & 7], OUTV); \
    OUTV = f4fma(g[6], ARR[((D) + 6) & 7], OUTV); }

#define VPASS2(D, OUTV, A, B) { \
    OUTV = f4scale(g[0], f4mul(A[(D) & 7], B[(D) & 7])); \
    OUTV = f4fma(g[1], f4mul(A[((D) + 1) & 7], B[((D) + 1) & 7]), OUTV); \
    OUTV = f4fma(g[2], f4mul(A[((D) + 2) & 7], B[((D) + 2) & 7]), OUTV); \
    OUTV = f4fma(g[3], f4mul(A[((D) + 3) & 7], B[((D) + 3) & 7]), OUTV); \
    OUTV = f4fma(g[4], f4mul(A[((D) + 4) & 7], B[((D) + 4) & 7]), OUTV); \
    OUTV = f4fma(g[5], f4mul(A[((D) + 5) & 7], B[((D) + 5) & 7]), OUTV); \
    OUTV = f4fma(g[6], f4mul(A[((D) + 6) & 7], B[((D) + 6) & 7]), OUTV); }

// horizontal 7-tap of V (float4): 6 bpermute halo cols + 4 fma chains
#define HCONV(V, OUT) { \
    float m3 = l0  ? 0.f : pullf(a_up, (V).y); \
    float m2 = l0  ? 0.f : pullf(a_up, (V).z); \
    float m1 = l0  ? 0.f : pullf(a_up, (V).w); \
    float q4 = l63 ? 0.f : pullf(a_dn, (V).x); \
    float q5 = l63 ? 0.f : pullf(a_dn, (V).y); \
    float q6 = l63 ? 0.f : pullf(a_dn, (V).z); \
    (OUT).x = fmaf(g[0], m3, fmaf(g[1], m2, fmaf(g[2], m1, fmaf(g[3], (V).x, \
              fmaf(g[4], (V).y, fmaf(g[5], (V).z, g[6] * (V).w)))))); \
    (OUT).y = fmaf(g[0], m2, fmaf(g[1], m1, fmaf(g[2], (V).x, fmaf(g[3], (V).y, \
              fmaf(g[4], (V).z, fmaf(g[5], (V).w, g[6] * q4)))))); \
    (OUT).z = fmaf(g[0], m1, fmaf(g[1], (V).x, fmaf(g[2], (V).y, fmaf(g[3], (V).z, \
              fmaf(g[4], (V).w, fmaf(g[5], q4, g[6] * q5)))))); \
    (OUT).w = fmaf(g[0], (V).x, fmaf(g[1], (V).y, fmaf(g[2], (V).z, fmaf(g[3], (V).w, \
              fmaf(g[4], q4, fmaf(g[5], q5, g[6] * q6)))))); }

// one output row r0+D. Quantities SEQUENTIAL: v is reused 5x so only the
// five h accumulators (20 regs) persist within the step.
#define STEP(D, DOLOAD) { \
    if (DOLOAD) { LOADROW(((D) + 7) & 7, r0 + (D) + 4); } \
    float4 v, h0, h1, h2, h3, h4; \
    VPASS1(D, v, WP);     HCONV(v, h0); \
    VPASS1(D, v, WT);     HCONV(v, h1); \
    VPASS2(D, v, WP, WP); HCONV(v, h2); \
    VPASS2(D, v, WT, WT); HCONV(v, h3); \
    VPASS2(D, v, WP, WT); HCONV(v, h4); \
    float s0_ = ssim1(h0.x, h1.x, h2.x, h3.x, h4.x); \
    float s1_ = ssim1(h0.y, h1.y, h2.y, h3.y, h4.y); \
    float s2_ = ssim1(h0.z, h1.z, h2.z, h3.z, h4.z); \
    float s3_ = ssim1(h0.w, h1.w, h2.w, h3.w, h4.w); \
    acc += (s0_ + s1_) + (s2_ + s3_); }

    // prologue: pure loads, rows r0-3 .. r0+3 -> slots 0..6
    LOADROW(0, r0 - 3) LOADROW(1, r0 - 2) LOADROW(2, r0 - 1)
    LOADROW(3, r0)     LOADROW(4, r0 + 1) LOADROW(5, r0 + 2)
    LOADROW(6, r0 + 3)

    STEP(0, 1) STEP(1, 1) STEP(2, 1) STEP(3, 1)
    STEP(4, 1) STEP(5, 1) STEP(6, 1) STEP(7, 0)

#undef LOADROW
#undef VPASS1
#undef VPASS2
#undef HCONV
#undef STEP

    // wave-local reduce, one write (or atomic) per wave
#pragma unroll
    for (int off = 32; off > 0; off >>= 1)
        acc += __shfl_xor(acc, off, 64);
    if (lane == 0) {
        if (ATOMIC) atomicAdd(&wsum[0], acc);
        else        wsum[gw] = acc;
    }
}

// deterministic f64 tree-reduce of the 4096 per-wave partials
__global__ __launch_bounds__(256) void ssim_final_arr(
    const float* __restrict__ ws, float* __restrict__ out)
{
    __shared__ double sred[4];
    double sm = 0.0;
#pragma unroll
    for (int k = 0; k < NWAVES / 256; ++k)
        sm += (double)ws[threadIdx.x + k * 256];
#pragma unroll
    for (int off = 32; off > 0; off >>= 1)
        sm += __shfl_down(sm, off, 64);
    const int lane = threadIdx.x & 63, wid = threadIdx.x >> 6;
    if (lane == 0) sred[wid] = sm;
    __syncthreads();
    if (threadIdx.x == 0) {
        double tot = sred[0] + sred[1] + sred[2] + sred[3];
        out[0] = (float)(1.0 - tot * (1.0 / (128.0 * 256.0 * 256.0)));
    }
}

__global__ void ssim_final_sc(const float* __restrict__ ws, float* __restrict__ out)
{
    out[0] = 1.0f - ws[0] * (1.0f / (128.0f * 256.0f * 256.0f));
}

extern "C" void kernel_launch(void* const* d_in, const int* in_sizes, int n_in,
                              void* d_out, int out_size, void* d_ws, size_t ws_size,
                              hipStream_t stream)
{
    const float* pred   = (const float*)d_in[0];
    const float* targ   = (const float*)d_in[1];
    const float* window = (const float*)d_in[2];
    float* out = (float*)d_out;
    float* ws  = (float*)d_ws;

    if (ws_size >= NWAVES * sizeof(float)) {
        // every ws slot is written by the grid each call: no memset needed
        ssim_main<0><<<NWAVES / 4, 256, 0, stream>>>(pred, targ, window, ws);
        ssim_final_arr<<<1, 256, 0, stream>>>(ws, out);
    } else {
        hipMemsetAsync(ws, 0, sizeof(float), stream);
        ssim_main<1><<<NWAVES / 4, 256, 0, stream>>>(pred, targ, window, ws);
        ssim_final_sc<<<1, 1, 0, stream>>>(ws, out);
    }
    (void)in_sizes; (void)n_in; (void)out_size;
}

// Round 6
// 76.404 us; speedup vs baseline: 3.7475x; 3.7413x over previous
//
#include <hip/hip_runtime.h>

#define IMG_H 256
#define IMG_W 256
#define ROWS 8
#define STRIPS (IMG_H / ROWS)      // 32 strips per image
#define NIMG 128
#define NWAVES (NIMG * STRIPS)     // 4096 waves, one per 8-row strip

__device__ __forceinline__ float pullf(int addr, float v) {
    return __int_as_float(__builtin_amdgcn_ds_bpermute(addr, __float_as_int(v)));
}

__device__ __forceinline__ float4 f4fma(float w, float4 a, float4 b) {
    return make_float4(fmaf(w, a.x, b.x), fmaf(w, a.y, b.y),
                       fmaf(w, a.z, b.z), fmaf(w, a.w, b.w));
}

__device__ __forceinline__ float4 f4mul(float4 a, float4 b) {
    return make_float4(a.x * b.x, a.y * b.y, a.z * b.z, a.w * b.w);
}

__device__ __forceinline__ float4 f4scale(float w, float4 a) {
    return make_float4(w * a.x, w * a.y, w * a.z, w * a.w);
}

__device__ __forceinline__ float ssim1(float mu1, float mu2, float spp, float stt, float spt) {
    const float C1 = 1e-4f, C2 = 9e-4f;
    float mu1s = mu1 * mu1, mu2s = mu2 * mu2, mu12 = mu1 * mu2;
    float s1 = spp - mu1s, s2 = stt - mu2s, s12 = spt - mu12;
    float num = (2.f * mu12 + C1) * (2.f * s12 + C2);
    float den = (mu1s + mu2s + C1) * (s1 + s2 + C2);
    return num * __builtin_amdgcn_rcpf(den);   // rel err ~1e-6; output is a mean -> negligible
}

// V-first separable SSIM. One wave = one 8-row strip, float4/lane = 256 cols.
// Window: RAW rows only (2 x 8 slots x float4 = 64 VGPR), mod-8 slots, all
// static indices. Quantities computed sequentially (v reused) -> peak live
// ~115 regs. NO min-waves launch bound: R4/R5 showed hipcc's
// amdgpu-waves-per-eu min triggers aggressive 64-reg allocation + full
// window spill (427 MB scratch writes). Natural allocation never spilled.
template<int ATOMIC>
__global__ __launch_bounds__(256) void ssim_main(
    const float* __restrict__ pred,
    const float* __restrict__ targ,
    const float* __restrict__ window,
    float* __restrict__ wsum)
{
    const int lane = threadIdx.x & 63;
    const int wid  = threadIdx.x >> 6;
    const int gw   = blockIdx.x * 4 + wid;   // 0..4095
    const int n    = gw >> 5;                // image
    const int s    = gw & 31;                // strip
    const int r0   = s * ROWS;
    const int c    = lane << 2;

    // exact 1D gaussian: g[j] = w2d[3][j] / sum_j w2d[3][j]
    float g[7];
    {
        float sum = 0.f;
#pragma unroll
        for (int j = 0; j < 7; ++j) { g[j] = window[21 + j]; sum += g[j]; }
        float inv = 1.f / sum;
#pragma unroll
        for (int j = 0; j < 7; ++j) g[j] *= inv;
    }

    const float* pn = pred + (size_t)n * (IMG_H * IMG_W) + c;
    const float* tn = targ + (size_t)n * (IMG_H * IMG_W) + c;

    const int a_up = ((lane - 1) & 63) << 2;
    const int a_dn = ((lane + 1) & 63) << 2;
    const bool l0  = (lane == 0);
    const bool l63 = (lane == 63);

    float4 WP[8], WT[8];        // slot = (j - (r0-3)) & 7
    float acc = 0.f;

#define LOADROW(SLOT, J) { \
    const int j_ = (J); \
    if ((unsigned)j_ < (unsigned)IMG_H) { \
        WP[SLOT] = *(const float4*)(pn + j_ * IMG_W); \
        WT[SLOT] = *(const float4*)(tn + j_ * IMG_W); \
    } else { \
        WP[SLOT] = make_float4(0.f, 0.f, 0.f, 0.f); \
        WT[SLOT] = make_float4(0.f, 0.f, 0.f, 0.f); \
    } }

#define VPASS1(D, OUTV, ARR) { \
    OUTV = f4scale(g[0], ARR[(D) & 7]); \
    OUTV = f4fma(g[1], ARR[((D) + 1) & 7], OUTV); \
    OUTV = f4fma(g[2], ARR[((D) + 2) & 7], OUTV); \
    OUTV = f4fma(g[3], ARR[((D) + 3) & 7], OUTV); \
    OUTV = f4fma(g[4], ARR[((D) + 4) & 7], OUTV); \
    OUTV = f4fma(g[5], ARR[((D) + 5) & 7], OUTV); \
    OUTV = f4fma(g[6], ARR[((D) + 6) & 7], OUTV); }

#define VPASS2(D, OUTV, A, B) { \
    OUTV = f4scale(g[0], f4mul(A[(D) & 7], B[(D) & 7])); \
    OUTV = f4fma(g[1], f4mul(A[((D) + 1) & 7], B[((D) + 1) & 7]), OUTV); \
    OUTV = f4fma(g[2], f4mul(A[((D) + 2) & 7], B[((D) + 2) & 7]), OUTV); \
    OUTV = f4fma(g[3], f4mul(A[((D) + 3) & 7], B[((D) + 3) & 7]), OUTV); \
    OUTV = f4fma(g[4], f4mul(A[((D) + 4) & 7], B[((D) + 4) & 7]), OUTV); \
    OUTV = f4fma(g[5], f4mul(A[((D) + 5) & 7], B[((D) + 5) & 7]), OUTV); \
    OUTV = f4fma(g[6], f4mul(A[((D) + 6) & 7], B[((D) + 6) & 7]), OUTV); }

// horizontal 7-tap of V (float4): 6 bpermute halo cols + 4 fma chains
#define HCONV(V, OUT) { \
    float m3 = l0  ? 0.f : pullf(a_up, (V).y); \
    float m2 = l0  ? 0.f : pullf(a_up, (V).z); \
    float m1 = l0  ? 0.f : pullf(a_up, (V).w); \
    float q4 = l63 ? 0.f : pullf(a_dn, (V).x); \
    float q5 = l63 ? 0.f : pullf(a_dn, (V).y); \
    float q6 = l63 ? 0.f : pullf(a_dn, (V).z); \
    (OUT).x = fmaf(g[0], m3, fmaf(g[1], m2, fmaf(g[2], m1, fmaf(g[3], (V).x, \
              fmaf(g[4], (V).y, fmaf(g[5], (V).z, g[6] * (V).w)))))); \
    (OUT).y = fmaf(g[0], m2, fmaf(g[1], m1, fmaf(g[2], (V).x, fmaf(g[3], (V).y, \
              fmaf(g[4], (V).z, fmaf(g[5], (V).w, g[6] * q4)))))); \
    (OUT).z = fmaf(g[0], m1, fmaf(g[1], (V).x, fmaf(g[2], (V).y, fmaf(g[3], (V).z, \
              fmaf(g[4], (V).w, fmaf(g[5], q4, g[6] * q5)))))); \
    (OUT).w = fmaf(g[0], (V).x, fmaf(g[1], (V).y, fmaf(g[2], (V).z, fmaf(g[3], (V).w, \
              fmaf(g[4], q4, fmaf(g[5], q5, g[6] * q6)))))); }

// one output row r0+D. Quantities SEQUENTIAL: v reused 5x, only the five
// h accumulators (20 regs) persist within the step.
#define STEP(D, DOLOAD) { \
    if (DOLOAD) { LOADROW(((D) + 7) & 7, r0 + (D) + 4); } \
    float4 v, h0, h1, h2, h3, h4; \
    VPASS1(D, v, WP);     HCONV(v, h0); \
    VPASS1(D, v, WT);     HCONV(v, h1); \
    VPASS2(D, v, WP, WP); HCONV(v, h2); \
    VPASS2(D, v, WT, WT); HCONV(v, h3); \
    VPASS2(D, v, WP, WT); HCONV(v, h4); \
    float s0_ = ssim1(h0.x, h1.x, h2.x, h3.x, h4.x); \
    float s1_ = ssim1(h0.y, h1.y, h2.y, h3.y, h4.y); \
    float s2_ = ssim1(h0.z, h1.z, h2.z, h3.z, h4.z); \
    float s3_ = ssim1(h0.w, h1.w, h2.w, h3.w, h4.w); \
    acc += (s0_ + s1_) + (s2_ + s3_); }

    // prologue: pure loads, rows r0-3 .. r0+3 -> slots 0..6
    LOADROW(0, r0 - 3) LOADROW(1, r0 - 2) LOADROW(2, r0 - 1)
    LOADROW(3, r0)     LOADROW(4, r0 + 1) LOADROW(5, r0 + 2)
    LOADROW(6, r0 + 3)

    STEP(0, 1) STEP(1, 1) STEP(2, 1) STEP(3, 1)
    STEP(4, 1) STEP(5, 1) STEP(6, 1) STEP(7, 0)

#undef LOADROW
#undef VPASS1
#undef VPASS2
#undef HCONV
#undef STEP

    // wave-local reduce, one write (or atomic) per wave
#pragma unroll
    for (int off = 32; off > 0; off >>= 1)
        acc += __shfl_xor(acc, off, 64);
    if (lane == 0) {
        if (ATOMIC) atomicAdd(&wsum[0], acc);
        else        wsum[gw] = acc;
    }
}

// deterministic f64 tree-reduce of the 4096 per-wave partials
__global__ __launch_bounds__(256) void ssim_final_arr(
    const float* __restrict__ ws, float* __restrict__ out)
{
    __shared__ double sred[4];
    double sm = 0.0;
#pragma unroll
    for (int k = 0; k < NWAVES / 256; ++k)
        sm += (double)ws[threadIdx.x + k * 256];
#pragma unroll
    for (int off = 32; off > 0; off >>= 1)
        sm += __shfl_down(sm, off, 64);
    const int lane = threadIdx.x & 63, wid = threadIdx.x >> 6;
    if (lane == 0) sred[wid] = sm;
    __syncthreads();
    if (threadIdx.x == 0) {
        double tot = sred[0] + sred[1] + sred[2] + sred[3];
        out[0] = (float)(1.0 - tot * (1.0 / (128.0 * 256.0 * 256.0)));
    }
}

__global__ void ssim_final_sc(const float* __restrict__ ws, float* __restrict__ out)
{
    out[0] = 1.0f - ws[0] * (1.0f / (128.0f * 256.0f * 256.0f));
}

extern "C" void kernel_launch(void* const* d_in, const int* in_sizes, int n_in,
                              void* d_out, int out_size, void* d_ws, size_t ws_size,
                              hipStream_t stream)
{
    const float* pred   = (const float*)d_in[0];
    const float* targ   = (const float*)d_in[1];
    const float* window = (const float*)d_in[2];
    float* out = (float*)d_out;
    float* ws  = (float*)d_ws;

    if (ws_size >= NWAVES * sizeof(float)) {
        // every ws slot is written by the grid each call: no memset needed
        ssim_main<0><<<NWAVES / 4, 256, 0, stream>>>(pred, targ, window, ws);
        ssim_final_arr<<<1, 256, 0, stream>>>(ws, out);
    } else {
        hipMemsetAsync(ws, 0, sizeof(float), stream);
        ssim_main<1><<<NWAVES / 4, 256, 0, stream>>>(pred, targ, window, ws);
        ssim_final_sc<<<1, 1, 0, stream>>>(ws, out);
    }
    (void)in_sizes; (void)n_in; (void)out_size;
}